// Round 7
// baseline (208.691 us; speedup 1.0000x reference)
//
#include <hip/hip_runtime.h>
#include <hip/hip_bf16.h>

// SE3 equivariant cross attention, MI355X gfx950. Round 7.
//  - attn: NSPLIT back to 16 (A/B: 32 splits was slower, occupancy not the
//    binder). K-fragment double-buffer prefetch + hoisted V loads to hide L2
//    latency under the elem loop (latency-bound per round-6 counters).
//  - proj: Q projection fused into the K/V kernel (one launch).
//  - epi: ow-GEMM + c1-GEMM share A-loads in one kernel; silu+c2 dot reduced
//    in-wave (shfl) -> atomicAdd cscale. coord finish is a trivial kernel.
//  - dispatches 9 -> 7 (incl. cscale memset).

#define NLIG   1024
#define NPOCK  8192
#define HIDDEN 256
#define ADIM   512
#define NHEAD  4
#define HDIM   64
#define NTAB   1024
#define NSPLIT 16
#define CHUNK  (NPOCK / NSPLIT)   // 512
#define NT     (CHUNK / 32)       // 16
#define LOG2E  1.4426950408889634f
#define QK_SCALE (0.125f * LOG2E)

typedef float f32x16 __attribute__((ext_vector_type(16)));
typedef short short8 __attribute__((ext_vector_type(8)));

union U4S8 { uint4 u; short8 s; };

static __device__ __forceinline__ float exp2h(float x) {
  float r; asm("v_exp_f32 %0, %1" : "=v"(r) : "v"(x)); return r;
}
static __device__ __forceinline__ float rsqh(float x) {
  float r; asm("v_rsq_f32 %0, %1" : "=v"(r) : "v"(x)); return r;
}
static __device__ __forceinline__ unsigned cvtpk(float lo, float hi) {
  unsigned r;
  asm("v_cvt_pk_bf16_f32 %0, %1, %2" : "=v"(r) : "v"(lo), "v"(hi));
  return r;
}
static __device__ __forceinline__ unsigned short f2bf(float f) {
  union { __hip_bfloat16 h; unsigned short u; } c;
  c.h = __float2bfloat16(f);
  return c.u;
}
static __device__ __forceinline__ float bf2f(unsigned u16) {
  union { unsigned uu; float f; } c;
  c.uu = u16 << 16;
  return c.f;
}
static __device__ __forceinline__ short8 load_bf8(const unsigned short* p) {
  U4S8 t; t.u = *(const uint4*)p; return t.s;
}
static __device__ __forceinline__ f32x16 mfma32(short8 a, short8 b, f32x16 c) {
  return __builtin_amdgcn_mfma_f32_32x32x16_bf16(a, b, c, 0, 0, 0);
}

// ---------------- prep: casts + weight transposes + edge table --------------
#define NCAST 4352
#define NTRANS 448
__global__ __launch_bounds__(256)
void prep_kernel(const float* __restrict__ hA, const float* __restrict__ hl,
                 const float* __restrict__ qw, const float* __restrict__ kw,
                 const float* __restrict__ vw, const float* __restrict__ ow,
                 const float* __restrict__ c1w,
                 const float* __restrict__ e1w, const float* __restrict__ e1b,
                 const float* __restrict__ e2w, const float* __restrict__ e2b,
                 unsigned short* __restrict__ hAb, unsigned short* __restrict__ hlb,
                 unsigned short* __restrict__ qwT, unsigned short* __restrict__ kwT,
                 unsigned short* __restrict__ vwT, unsigned short* __restrict__ owT,
                 unsigned short* __restrict__ c1wT, float* __restrict__ tabG) {
  int bx = blockIdx.x;
  int tid = threadIdx.x;
  if (bx < NCAST) {
    int id = bx * 256 + tid;
    const int nA4 = NPOCK * ADIM / 4;
    if (id < nA4) {
      float4 v = ((const float4*)hA)[id];
      ushort4 o; o.x = f2bf(v.x); o.y = f2bf(v.y); o.z = f2bf(v.z); o.w = f2bf(v.w);
      ((ushort4*)hAb)[id] = o;
    } else {
      int j = id - nA4;
      float4 v = ((const float4*)hl)[j];
      ushort4 o; o.x = f2bf(v.x); o.y = f2bf(v.y); o.z = f2bf(v.z); o.w = f2bf(v.w);
      ((ushort4*)hlb)[j] = o;
    }
  } else if (bx < NCAST + NTRANS) {
    int b = bx - NCAST;
    const float* src; unsigned short* dst; int K;
    if (b < 64)       { src = qw;  dst = qwT;  K = 256; }
    else if (b < 192) { src = kw;  dst = kwT;  K = 512; b -= 64; }
    else if (b < 320) { src = vw;  dst = vwT;  K = 512; b -= 192; }
    else if (b < 384) { src = ow;  dst = owT;  K = 256; b -= 320; }
    else              { src = c1w; dst = c1wT; K = 256; b -= 384; }
    int kt = K / 32;
    int k0 = (b % kt) * 32, n0 = (b / kt) * 32;
    __shared__ float tile[32][33];
    int tx = tid & 31, ty = tid >> 5;
#pragma unroll
    for (int r = 0; r < 4; ++r)
      tile[ty + 8 * r][tx] = src[(k0 + ty + 8 * r) * 256 + n0 + tx];
    __syncthreads();
#pragma unroll
    for (int r = 0; r < 4; ++r)
      dst[(n0 + ty + 8 * r) * K + k0 + tx] = f2bf(tile[tx][ty + 8 * r]);
  } else {
    int eb = bx - (NCAST + NTRANS);
    int w = tid >> 6, l = tid & 63;
    int entry = eb * 4 + w;
    float d = (entry + 0.5f) * (10.0f / NTAB);
    float a0 = 0.f, a1 = 0.f, a2 = 0.f, a3 = 0.f;
#pragma unroll
    for (int jj = 0; jj < 4; ++jj) {
      int j = l + jj * 64;
      float v = fmaf(d, e1w[j], e1b[j]);
      float s = v / (1.0f + __expf(-v));
      float4 w2 = ((const float4*)e2w)[j];
      a0 = fmaf(s, w2.x, a0);
      a1 = fmaf(s, w2.y, a1);
      a2 = fmaf(s, w2.z, a2);
      a3 = fmaf(s, w2.w, a3);
    }
#pragma unroll
    for (int m = 32; m >= 1; m >>= 1) {
      a0 += __shfl_xor(a0, m); a1 += __shfl_xor(a1, m);
      a2 += __shfl_xor(a2, m); a3 += __shfl_xor(a3, m);
    }
    if (l == 0) {
      tabG[0 * NTAB + entry] = (a0 + e2b[0]) * LOG2E;
      tabG[1 * NTAB + entry] = (a1 + e2b[1]) * LOG2E;
      tabG[2 * NTAB + entry] = (a2 + e2b[2]) * LOG2E;
      tabG[3 * NTAB + entry] = (a3 + e2b[3]) * LOG2E;
    }
  }
}

// ------------- fused projections: K,V (shared A) and Q ----------------------
// grid (72, 8): bx<64 -> K/V over NPOCK; bx in [64,72) -> Q over NLIG.
__global__ __launch_bounds__(256)
void proj_kernel(const unsigned short* __restrict__ hAb, const unsigned short* __restrict__ hlb,
                 const unsigned short* __restrict__ kwT, const unsigned short* __restrict__ vwT,
                 const unsigned short* __restrict__ qwT,
                 const float* __restrict__ kb, const float* __restrict__ vb,
                 const float* __restrict__ qb,
                 unsigned short* __restrict__ Kb, unsigned short* __restrict__ VTb,
                 unsigned short* __restrict__ Qb) {
  int tid = threadIdx.x;
  int w = tid >> 6, lane = tid & 63;
  int lo = lane & 31, hi = lane >> 5;
  int n0 = blockIdx.y * 32;
  int n = n0 + lo;
  if (blockIdx.x < 64) {
    int m0 = blockIdx.x * 128 + w * 32;
    const unsigned short* ap  = hAb + (size_t)(m0 + lo) * ADIM + hi * 8;
    const unsigned short* bkp = kwT + (size_t)n * ADIM + hi * 8;
    const unsigned short* bvp = vwT + (size_t)n * ADIM + hi * 8;
    f32x16 aK, aV;
#pragma unroll
    for (int i = 0; i < 16; ++i) { aK[i] = 0.f; aV[i] = 0.f; }
#pragma unroll 8
    for (int kk = 0; kk < ADIM / 16; ++kk) {
      short8 a  = load_bf8(ap + kk * 16);
      short8 bk = load_bf8(bkp + kk * 16);
      short8 bv = load_bf8(bvp + kk * 16);
      aK = mfma32(a, bk, aK);      // C[m][n]
      aV = mfma32(bv, a, aV);      // swapped: C[n][m] -> coalesced V^T store
    }
    float bnK = kb[n];
#pragma unroll
    for (int g = 0; g < 4; ++g) {
#pragma unroll
      for (int rr = 0; rr < 4; ++rr) {
        int r = g * 4 + rr;
        int row = g * 8 + hi * 4 + rr;
        Kb[(size_t)(m0 + row) * HIDDEN + n] = f2bf(aK[r] + bnK);
        int nv = n0 + row;
        VTb[(size_t)nv * NPOCK + m0 + lo] = f2bf(aV[r] + vb[nv]);
      }
    }
  } else {
    int m0 = (blockIdx.x - 64) * 128 + w * 32;
    const unsigned short* ap = hlb + (size_t)(m0 + lo) * HIDDEN + hi * 8;
    const unsigned short* bp = qwT + (size_t)n * HIDDEN + hi * 8;
    f32x16 acc;
#pragma unroll
    for (int i = 0; i < 16; ++i) acc[i] = 0.f;
#pragma unroll 8
    for (int kk = 0; kk < HIDDEN / 16; ++kk) {
      short8 a = load_bf8(ap + kk * 16);
      short8 b = load_bf8(bp + kk * 16);
      acc = mfma32(a, b, acc);
    }
    float bn = qb[n];
#pragma unroll
    for (int g = 0; g < 4; ++g) {
#pragma unroll
      for (int rr = 0; rr < 4; ++rr) {
        int r = g * 4 + rr;
        int m = m0 + g * 8 + hi * 4 + rr;
        Qb[(size_t)m * HIDDEN + n] = f2bf(acc[r] + bn);
      }
    }
  }
}

// ------------- flash cross-attention with geometry --------------------------
// grid: 32 q-tiles * 16 splits; block: 4 waves = 4 heads.
// K-fragment double-buffer prefetch + hoisted V loads (latency-bound fix).
__global__ __launch_bounds__(256)
void attn_kernel(const unsigned short* __restrict__ Qbf, const unsigned short* __restrict__ Kbf,
                 const unsigned short* __restrict__ VTbf,
                 const float* __restrict__ x_lig, const float* __restrict__ x_pocket,
                 const float* __restrict__ tabG,
                 unsigned* __restrict__ partOb, float4* __restrict__ partZC) {
  __shared__ float4 xch[CHUNK];            // 8 KB
  __shared__ float tab[NHEAD][NTAB];       // 16 KB

  int tid = threadIdx.x;
  int h = tid >> 6;
  int lane = tid & 63;
  int lo = lane & 31, hi = lane >> 5;
  int qt = blockIdx.x & 31;
  int split = blockIdx.x >> 5;
  int q0 = qt * 32;
  int j0g = split * CHUNK;

  for (int i = tid; i < CHUNK; i += 256) {
    float x = x_pocket[(j0g + i) * 3 + 0];
    float y = x_pocket[(j0g + i) * 3 + 1];
    float z = x_pocket[(j0g + i) * 3 + 2];
    float4 v; v.x = x; v.y = y; v.z = z; v.w = 0.f;
    xch[i] = v;
  }
  for (int i = tid; i < NHEAD * NTAB; i += 256) ((float*)tab)[i] = tabG[i];
  __syncthreads();

  int q = q0 + lo;
  float xl0 = x_lig[q * 3 + 0];
  float xl1 = x_lig[q * 3 + 1];
  float xl2 = x_lig[q * 3 + 2];

  short8 qfr[4];
#pragma unroll
  for (int kk = 0; kk < 4; ++kk)
    qfr[kk] = load_bf8(Qbf + (size_t)q * HIDDEN + h * HDIM + kk * 16 + hi * 8);

  const unsigned short* kbp = Kbf + (size_t)(j0g + lo) * HIDDEN + h * HDIM + hi * 8;
  const unsigned short* vbp = VTbf + (size_t)(h * HDIM + lo) * NPOCK + j0g + hi * 8;

  f32x16 O0, O1;
#pragma unroll
  for (int i = 0; i < 16; ++i) { O0[i] = 0.f; O1[i] = 0.f; }
  float Z = 0.f, c0 = 0.f, c1 = 0.f, c2 = 0.f;

  short8 kcur[4];
#pragma unroll
  for (int kk = 0; kk < 4; ++kk) kcur[kk] = load_bf8(kbp + kk * 16);

#pragma unroll 1
  for (int t = 0; t < NT; ++t) {
    int jb = t * 32;
    // prefetch next K tile (clamped redundant load on last iter)
    int tn = (t + 1 < NT) ? (t + 1) : t;
    short8 knx0 = load_bf8(kbp + (size_t)tn * 32 * HIDDEN + 0 * 16);
    short8 knx1 = load_bf8(kbp + (size_t)tn * 32 * HIDDEN + 1 * 16);
    short8 knx2 = load_bf8(kbp + (size_t)tn * 32 * HIDDEN + 2 * 16);
    short8 knx3 = load_bf8(kbp + (size_t)tn * 32 * HIDDEN + 3 * 16);
    // hoist V loads for this iter: covered by the elem-loop latency
    short8 v00 = load_bf8(vbp + jb);
    short8 v01 = load_bf8(vbp + jb + (size_t)32 * NPOCK);
    short8 v10 = load_bf8(vbp + jb + 16);
    short8 v11 = load_bf8(vbp + jb + 16 + (size_t)32 * NPOCK);

    f32x16 s;
#pragma unroll
    for (int i = 0; i < 16; ++i) s[i] = 0.f;
    s = mfma32(kcur[0], qfr[0], s);
    s = mfma32(kcur[1], qfr[1], s);
    s = mfma32(kcur[2], qfr[2], s);
    s = mfma32(kcur[3], qfr[3], s);

    unsigned wp[8];
    float pprev = 0.f;
#pragma unroll
    for (int r = 0; r < 16; ++r) {
      int jl = (r & 3) + 8 * (r >> 2) + 4 * hi;
      float4 xp = xch[jb + jl];
      float dx = xp.x - xl0, dy = xp.y - xl1, dz = xp.z - xl2;
      float r2 = fmaf(dx, dx, fmaf(dy, dy, dz * dz));
      float r2c = fmaxf(r2, 1e-24f);
      float rinv = rsqh(r2c);
      float d = r2c * rinv;
      int idx = (int)(d * (NTAB / 10.0f));
      idx = idx > (NTAB - 1) ? (NTAB - 1) : idx;
      float b = tab[h][idx];
      float s2 = fmaf(s[r], QK_SCALE, b);
      float pe = (r2 < 100.0f) ? exp2h(s2) : 0.0f;
      Z += pe;
      float pr = pe * rinv;
      c0 = fmaf(pr, dx, c0);
      c1 = fmaf(pr, dy, c1);
      c2 = fmaf(pr, dz, c2);
      if (r & 1) wp[r >> 1] = cvtpk(pprev, pe); else pprev = pe;
    }
    // P^T -> B fragments and PV
    {
      unsigned W0 = wp[0], W1 = wp[1], W2 = wp[2], W3 = wp[3];
      unsigned e01 = (unsigned)__shfl_xor((int)(hi ? W0 : W2), 32);
      unsigned e23 = (unsigned)__shfl_xor((int)(hi ? W1 : W3), 32);
      U4S8 pb;
      pb.u.x = hi ? e01 : W0;
      pb.u.y = hi ? e23 : W1;
      pb.u.z = hi ? W2 : e01;
      pb.u.w = hi ? W3 : e23;
      O0 = mfma32(v00, pb.s, O0);
      O1 = mfma32(v01, pb.s, O1);
    }
    {
      unsigned W0 = wp[4], W1 = wp[5], W2 = wp[6], W3 = wp[7];
      unsigned e01 = (unsigned)__shfl_xor((int)(hi ? W0 : W2), 32);
      unsigned e23 = (unsigned)__shfl_xor((int)(hi ? W1 : W3), 32);
      U4S8 pb;
      pb.u.x = hi ? e01 : W0;
      pb.u.y = hi ? e23 : W1;
      pb.u.z = hi ? W2 : e01;
      pb.u.w = hi ? W3 : e23;
      O0 = mfma32(v10, pb.s, O0);
      O1 = mfma32(v11, pb.s, O1);
    }
    kcur[0] = knx0; kcur[1] = knx1; kcur[2] = knx2; kcur[3] = knx3;
  }

  unsigned* po = partOb + (size_t)(((q * NHEAD) + h) * NSPLIT + split) * (HDIM / 2);
#pragma unroll
  for (int g = 0; g < 4; ++g) {
    uint2 u0;
    u0.x = cvtpk(O0[g * 4 + 0], O0[g * 4 + 1]);
    u0.y = cvtpk(O0[g * 4 + 2], O0[g * 4 + 3]);
    *(uint2*)(po + (g * 8 + hi * 4) / 2) = u0;
    uint2 u1;
    u1.x = cvtpk(O1[g * 4 + 0], O1[g * 4 + 1]);
    u1.y = cvtpk(O1[g * 4 + 2], O1[g * 4 + 3]);
    *(uint2*)(po + (32 + g * 8 + hi * 4) / 2) = u1;
  }
  float Zt = Z + __shfl_xor(Z, 32);
  float c0t = c0 + __shfl_xor(c0, 32);
  float c1t = c1 + __shfl_xor(c1, 32);
  float c2t = c2 + __shfl_xor(c2, 32);
  if (hi == 0) {
    float4 zc; zc.x = Zt; zc.y = c0t; zc.z = c1t; zc.w = c2t;
    partZC[((q * NHEAD) + h) * NSPLIT + split] = zc;
  }
}

// ------------- combine splits -> h_attended (bf16) + coord messages ---------
__global__ __launch_bounds__(256)
void combine_kernel(const unsigned short* __restrict__ partOb, const float4* __restrict__ partZC,
                    unsigned short* __restrict__ hattb, float* __restrict__ cmsg) {
  int q = blockIdx.x;
  int t = threadIdx.x;
  int h = t >> 6, dl = t & 63;
  float Zh = 0.f;
#pragma unroll
  for (int s = 0; s < NSPLIT; ++s) Zh += partZC[(q * NHEAD + h) * NSPLIT + s].x;
  float o = 0.f;
#pragma unroll
  for (int s = 0; s < NSPLIT; ++s)
    o += bf2f(partOb[(size_t)((q * NHEAD + h) * NSPLIT + s) * HDIM + dl]);
  float inv = (Zh > 0.f) ? 1.0f / Zh : 0.f;
  hattb[(size_t)q * HIDDEN + h * HDIM + dl] = f2bf(o * inv);

  __shared__ float sm[NHEAD][3];
  if (t < NHEAD) {
    float zz = 0.f, a0 = 0.f, a1 = 0.f, a2 = 0.f;
    for (int s = 0; s < NSPLIT; ++s) {
      float4 v = partZC[(q * NHEAD + t) * NSPLIT + s];
      zz += v.x; a0 += v.y; a1 += v.z; a2 += v.w;
    }
    float iv = (zz > 0.f) ? 0.25f / zz : 0.f;
    sm[t][0] = a0 * iv; sm[t][1] = a1 * iv; sm[t][2] = a2 * iv;
  }
  __syncthreads();
  if (t < 3) cmsg[q * 3 + t] = sm[0][t] + sm[1][t] + sm[2][t] + sm[3][t];
}

// ------------- fused epilogue: hout = hatt@ow + ob + resid ;  cscale --------
// grid (8,8), 4 waves. Shared A-loads feed both ow and c1 GEMMs; silu+c2 dot
// reduced across the 32-lane half via shfl, atomicAdd into cscale[m].
__global__ __launch_bounds__(256)
void epi_kernel(const unsigned short* __restrict__ hatt,
                const unsigned short* __restrict__ owT, const unsigned short* __restrict__ c1wT,
                const float* __restrict__ ob, const float* __restrict__ c1b,
                const float* __restrict__ c2w, const float* __restrict__ h_lig,
                float* __restrict__ hout, float* __restrict__ cscale) {
  int tid = threadIdx.x;
  int w = tid >> 6, lane = tid & 63;
  int lo = lane & 31, hi = lane >> 5;
  int m0 = blockIdx.x * 128 + w * 32;
  int n0 = blockIdx.y * 32;
  int n = n0 + lo;
  const unsigned short* ap = hatt + (size_t)(m0 + lo) * HIDDEN + hi * 8;
  const unsigned short* bo = owT + (size_t)n * HIDDEN + hi * 8;
  const unsigned short* bc = c1wT + (size_t)n * HIDDEN + hi * 8;
  f32x16 aO, aC;
#pragma unroll
  for (int i = 0; i < 16; ++i) { aO[i] = 0.f; aC[i] = 0.f; }
#pragma unroll 8
  for (int kk = 0; kk < HIDDEN / 16; ++kk) {
    short8 a  = load_bf8(ap + kk * 16);
    short8 b1 = load_bf8(bo + kk * 16);
    short8 b2 = load_bf8(bc + kk * 16);
    aO = mfma32(a, b1, aO);
    aC = mfma32(a, b2, aC);
  }
  float obn = ob[n], c1bn = c1b[n], c2wn = c2w[n];
#pragma unroll
  for (int g = 0; g < 4; ++g) {
#pragma unroll
    for (int rr = 0; rr < 4; ++rr) {
      int r = g * 4 + rr;
      int m = m0 + g * 8 + hi * 4 + rr;
      hout[(size_t)m * HIDDEN + n] = aO[r] + obn + h_lig[(size_t)m * HIDDEN + n];
      float v = aC[r] + c1bn;
      float sg = v / (1.0f + exp2h(-LOG2E * v));
      float part = sg * c2wn;
#pragma unroll
      for (int msk = 16; msk >= 1; msk >>= 1) part += __shfl_xor(part, msk);
      if (lo == 0) atomicAdd(&cscale[m], part);
    }
  }
}

// ------------- coord finish: x_out = x_lig + (cscale+c2b)*cmsg --------------
__global__ __launch_bounds__(256)
void coordfin_kernel(const float* __restrict__ cscale, const float* __restrict__ c2b,
                     const float* __restrict__ cmsg, const float* __restrict__ x_lig,
                     float* __restrict__ x_out) {
  int id = blockIdx.x * 256 + threadIdx.x;
  if (id < NLIG * 3) {
    int q = id / 3;
    x_out[id] = x_lig[id] + (cscale[q] + c2b[0]) * cmsg[id];
  }
}

extern "C" void kernel_launch(void* const* d_in, const int* in_sizes, int n_in,
                              void* d_out, int out_size, void* d_ws, size_t ws_size,
                              hipStream_t stream) {
  const float* h_lig  = (const float*)d_in[0];
  const float* x_lig  = (const float*)d_in[1];
  const float* h_atom = (const float*)d_in[2];
  const float* x_pock = (const float*)d_in[3];
  const float* qw  = (const float*)d_in[4];
  const float* qb  = (const float*)d_in[5];
  const float* kw  = (const float*)d_in[6];
  const float* kb  = (const float*)d_in[7];
  const float* vw  = (const float*)d_in[8];
  const float* vb  = (const float*)d_in[9];
  const float* ow  = (const float*)d_in[10];
  const float* ob  = (const float*)d_in[11];
  const float* e1w = (const float*)d_in[12];
  const float* e1b = (const float*)d_in[13];
  const float* e2w = (const float*)d_in[14];
  const float* e2b = (const float*)d_in[15];
  const float* c1w = (const float*)d_in[16];
  const float* c1b = (const float*)d_in[17];
  const float* c2w = (const float*)d_in[18];
  const float* c2b = (const float*)d_in[19];

  char* w = (char*)d_ws;
  unsigned short* hAb  = (unsigned short*)w; w += (size_t)NPOCK * ADIM * 2;
  unsigned short* hlb  = (unsigned short*)w; w += (size_t)NLIG * HIDDEN * 2;
  unsigned short* qwT  = (unsigned short*)w; w += 256 * 256 * 2;
  unsigned short* kwT  = (unsigned short*)w; w += 256 * 512 * 2;
  unsigned short* vwT  = (unsigned short*)w; w += 256 * 512 * 2;
  unsigned short* owT  = (unsigned short*)w; w += 256 * 256 * 2;
  unsigned short* c1wT = (unsigned short*)w; w += 256 * 256 * 2;
  unsigned short* Qb   = (unsigned short*)w; w += (size_t)NLIG * HIDDEN * 2;
  unsigned short* Kb   = (unsigned short*)w; w += (size_t)NPOCK * HIDDEN * 2;
  unsigned short* VTb  = (unsigned short*)w; w += (size_t)HIDDEN * NPOCK * 2;
  float* tabG          = (float*)w;          w += NHEAD * NTAB * 4;
  unsigned* partOb     = (unsigned*)w;       w += (size_t)NLIG * NHEAD * NSPLIT * HDIM * 2;
  float* partZC        = (float*)w;          w += (size_t)NLIG * NHEAD * NSPLIT * 4 * 4;
  unsigned short* hatt = (unsigned short*)w; w += (size_t)NLIG * HIDDEN * 2;
  float* cmsg          = (float*)w;          w += (size_t)NLIG * 3 * 4;
  float* cscale        = (float*)w;          w += (size_t)NLIG * 4;

  float* hout = (float*)d_out;
  float* xout = ((float*)d_out) + (size_t)NLIG * HIDDEN;

  prep_kernel<<<NCAST + NTRANS + NTAB / 4, 256, 0, stream>>>(
      h_atom, h_lig, qw, kw, vw, ow, c1w, e1w, e1b, e2w, e2b,
      hAb, hlb, qwT, kwT, vwT, owT, c1wT, tabG);
  proj_kernel<<<dim3(72, 8), 256, 0, stream>>>(
      hAb, hlb, kwT, vwT, qwT, kb, vb, qb, Kb, VTb, Qb);
  attn_kernel<<<32 * NSPLIT, 256, 0, stream>>>(Qb, Kb, VTb, x_lig, x_pock, tabG,
                                               partOb, (float4*)partZC);
  combine_kernel<<<NLIG, 256, 0, stream>>>((const unsigned short*)partOb,
                                           (const float4*)partZC, hatt, cmsg);
  hipMemsetAsync(cscale, 0, NLIG * sizeof(float), stream);
  epi_kernel<<<dim3(8, 8), 256, 0, stream>>>(hatt, owT, c1wT, ob, c1b, c2w, h_lig,
                                             hout, cscale);
  coordfin_kernel<<<(NLIG * 3 + 255) / 256, 256, 0, stream>>>(cscale, c2b, cmsg,
                                                              x_lig, xout);
}

// Round 8
// 182.717 us; speedup vs baseline: 1.1422x; 1.1422x over previous
//
#include <hip/hip_runtime.h>
#include <hip/hip_bf16.h>

// SE3 equivariant cross attention, MI355X gfx950. Round 8.
// Theme: kill 64-line transaction amplification. ALL MFMA operands stored in
// tile-8 fragment-major layout: addr(r,c) = ((r>>5)*(C/8)+(c>>3))*256
// + (r&31)*8 + (c&7)  -> every wave's operand load is 1KB contiguous.
// partO -> [split][q][c] so combine reads coalesced.
// attn structure (4-wave/NSPLIT=16/prefetch) kept from round 7.

#define NLIG   1024
#define NPOCK  8192
#define HIDDEN 256
#define ADIM   512
#define NHEAD  4
#define HDIM   64
#define NTAB   1024
#define NSPLIT 16
#define CHUNK  (NPOCK / NSPLIT)   // 512
#define NT     (CHUNK / 32)       // 16
#define LOG2E  1.4426950408889634f
#define QK_SCALE (0.125f * LOG2E)

typedef float f32x16 __attribute__((ext_vector_type(16)));
typedef short short8 __attribute__((ext_vector_type(8)));

union U4S8 { uint4 u; short8 s; };

static __device__ __forceinline__ float exp2h(float x) {
  float r; asm("v_exp_f32 %0, %1" : "=v"(r) : "v"(x)); return r;
}
static __device__ __forceinline__ float rsqh(float x) {
  float r; asm("v_rsq_f32 %0, %1" : "=v"(r) : "v"(x)); return r;
}
static __device__ __forceinline__ unsigned cvtpk(float lo, float hi) {
  unsigned r;
  asm("v_cvt_pk_bf16_f32 %0, %1, %2" : "=v"(r) : "v"(lo), "v"(hi));
  return r;
}
static __device__ __forceinline__ unsigned short f2bf(float f) {
  union { __hip_bfloat16 h; unsigned short u; } c;
  c.h = __float2bfloat16(f);
  return c.u;
}
static __device__ __forceinline__ float bf2f(unsigned u16) {
  union { unsigned uu; float f; } c;
  c.uu = u16 << 16;
  return c.f;
}
static __device__ __forceinline__ short8 load_bf8(const unsigned short* p) {
  U4S8 t; t.u = *(const uint4*)p; return t.s;
}
static __device__ __forceinline__ f32x16 mfma32(short8 a, short8 b, f32x16 c) {
  return __builtin_amdgcn_mfma_f32_32x32x16_bf16(a, b, c, 0, 0, 0);
}
// tile-8 fragment-major layout: 32x8 tiles, row-block major.
static __device__ __forceinline__ size_t t8(int r, int c, int Cdiv8) {
  return ((size_t)((r >> 5) * Cdiv8 + (c >> 3)) << 8) + ((r & 31) << 3) + (c & 7);
}

// ---------------- prep: casts + weight transposes + edge table --------------
#define NCAST 4352
#define NTRANS 448
__global__ __launch_bounds__(256)
void prep_kernel(const float* __restrict__ hA, const float* __restrict__ hl,
                 const float* __restrict__ qw, const float* __restrict__ kw,
                 const float* __restrict__ vw, const float* __restrict__ ow,
                 const float* __restrict__ c1w,
                 const float* __restrict__ e1w, const float* __restrict__ e1b,
                 const float* __restrict__ e2w, const float* __restrict__ e2b,
                 unsigned short* __restrict__ hAb, unsigned short* __restrict__ hlb,
                 unsigned short* __restrict__ qwT, unsigned short* __restrict__ kwT,
                 unsigned short* __restrict__ vwT, unsigned short* __restrict__ owT,
                 unsigned short* __restrict__ c1wT, float* __restrict__ tabG) {
  int bx = blockIdx.x;
  int tid = threadIdx.x;
  if (bx < NCAST) {
    int id = bx * 256 + tid;
    const int nA4 = NPOCK * ADIM / 4;
    if (id < nA4) {
      float4 v = ((const float4*)hA)[id];
      int r = id >> 7, c0 = (id << 2) & 511;          // ADIM=512
      ushort4 o; o.x = f2bf(v.x); o.y = f2bf(v.y); o.z = f2bf(v.z); o.w = f2bf(v.w);
      *(ushort4*)(hAb + t8(r, c0, 64)) = o;
    } else {
      int j = id - nA4;
      float4 v = ((const float4*)hl)[j];
      int r = j >> 6, c0 = (j << 2) & 255;            // HIDDEN=256
      ushort4 o; o.x = f2bf(v.x); o.y = f2bf(v.y); o.z = f2bf(v.z); o.w = f2bf(v.w);
      *(ushort4*)(hlb + t8(r, c0, 32)) = o;
    }
  } else if (bx < NCAST + NTRANS) {
    int b = bx - NCAST;
    const float* src; unsigned short* dst; int K;
    if (b < 64)       { src = qw;  dst = qwT;  K = 256; }
    else if (b < 192) { src = kw;  dst = kwT;  K = 512; b -= 64; }
    else if (b < 320) { src = vw;  dst = vwT;  K = 512; b -= 192; }
    else if (b < 384) { src = ow;  dst = owT;  K = 256; b -= 320; }
    else              { src = c1w; dst = c1wT; K = 256; b -= 384; }
    int kt = K / 32;
    int k0 = (b % kt) * 32, n0 = (b / kt) * 32;
    __shared__ float tile[32][33];
    int tx = tid & 31, ty = tid >> 5;
#pragma unroll
    for (int r = 0; r < 4; ++r)
      tile[ty + 8 * r][tx] = src[(k0 + ty + 8 * r) * 256 + n0 + tx];
    __syncthreads();
#pragma unroll
    for (int r = 0; r < 4; ++r)
      dst[t8(n0 + ty + 8 * r, k0 + tx, K >> 3)] = f2bf(tile[tx][ty + 8 * r]);
  } else {
    int eb = bx - (NCAST + NTRANS);
    int w = tid >> 6, l = tid & 63;
    int entry = eb * 4 + w;
    float d = (entry + 0.5f) * (10.0f / NTAB);
    float a0 = 0.f, a1 = 0.f, a2 = 0.f, a3 = 0.f;
#pragma unroll
    for (int jj = 0; jj < 4; ++jj) {
      int j = l + jj * 64;
      float v = fmaf(d, e1w[j], e1b[j]);
      float s = v / (1.0f + __expf(-v));
      float4 w2 = ((const float4*)e2w)[j];
      a0 = fmaf(s, w2.x, a0);
      a1 = fmaf(s, w2.y, a1);
      a2 = fmaf(s, w2.z, a2);
      a3 = fmaf(s, w2.w, a3);
    }
#pragma unroll
    for (int m = 32; m >= 1; m >>= 1) {
      a0 += __shfl_xor(a0, m); a1 += __shfl_xor(a1, m);
      a2 += __shfl_xor(a2, m); a3 += __shfl_xor(a3, m);
    }
    if (l == 0) {
      tabG[0 * NTAB + entry] = (a0 + e2b[0]) * LOG2E;
      tabG[1 * NTAB + entry] = (a1 + e2b[1]) * LOG2E;
      tabG[2 * NTAB + entry] = (a2 + e2b[2]) * LOG2E;
      tabG[3 * NTAB + entry] = (a3 + e2b[3]) * LOG2E;
    }
  }
}

// ------------- fused projections: K,V (shared A) and Q ----------------------
__global__ __launch_bounds__(256)
void proj_kernel(const unsigned short* __restrict__ hAb, const unsigned short* __restrict__ hlb,
                 const unsigned short* __restrict__ kwT, const unsigned short* __restrict__ vwT,
                 const unsigned short* __restrict__ qwT,
                 const float* __restrict__ kb, const float* __restrict__ vb,
                 const float* __restrict__ qb,
                 unsigned short* __restrict__ Kb, unsigned short* __restrict__ VTb,
                 unsigned short* __restrict__ Qb) {
  int tid = threadIdx.x;
  int w = tid >> 6, lane = tid & 63;
  int lo = lane & 31, hi = lane >> 5;
  int n0 = blockIdx.y * 32;
  int n = n0 + lo;
  if (blockIdx.x < 64) {
    int m0 = blockIdx.x * 128 + w * 32;
    const unsigned short* ap  = hAb + t8(m0 + lo, hi * 8, 64);
    const unsigned short* bkp = kwT + t8(n, hi * 8, 64);
    const unsigned short* bvp = vwT + t8(n, hi * 8, 64);
    f32x16 aK, aV;
#pragma unroll
    for (int i = 0; i < 16; ++i) { aK[i] = 0.f; aV[i] = 0.f; }
#pragma unroll 8
    for (int kk = 0; kk < ADIM / 16; ++kk) {
      short8 a  = load_bf8(ap + kk * 512);     // two tiles (hi) per kk -> +512
      short8 bk = load_bf8(bkp + kk * 512);
      short8 bv = load_bf8(bvp + kk * 512);
      aK = mfma32(a, bk, aK);      // C[m][n]
      aV = mfma32(bv, a, aV);      // swapped: C[n][m]
    }
    float bnK = kb[n];
#pragma unroll
    for (int g = 0; g < 4; ++g) {
#pragma unroll
      for (int rr = 0; rr < 4; ++rr) {
        int r = g * 4 + rr;
        int row = g * 8 + hi * 4 + rr;
        Kb[t8(m0 + row, n, 32)] = f2bf(aK[r] + bnK);
        int nv = n0 + row;
        VTb[t8(nv, m0 + lo, 1024)] = f2bf(aV[r] + vb[nv]);
      }
    }
  } else {
    int m0 = (blockIdx.x - 64) * 128 + w * 32;
    const unsigned short* ap = hlb + t8(m0 + lo, hi * 8, 32);
    const unsigned short* bp = qwT + t8(n, hi * 8, 32);
    f32x16 acc;
#pragma unroll
    for (int i = 0; i < 16; ++i) acc[i] = 0.f;
#pragma unroll 8
    for (int kk = 0; kk < HIDDEN / 16; ++kk) {
      short8 a = load_bf8(ap + kk * 512);
      short8 b = load_bf8(bp + kk * 512);
      acc = mfma32(a, b, acc);
    }
    float bn = qb[n];
#pragma unroll
    for (int g = 0; g < 4; ++g) {
#pragma unroll
      for (int rr = 0; rr < 4; ++rr) {
        int r = g * 4 + rr;
        int m = m0 + g * 8 + hi * 4 + rr;
        Qb[t8(m, n, 32)] = f2bf(acc[r] + bn);
      }
    }
  }
}

// ------------- flash cross-attention with geometry --------------------------
// grid: 32 q-tiles * 16 splits; block: 4 waves = 4 heads. All operand loads
// are 1KB-contiguous (tile-8 layouts).
__global__ __launch_bounds__(256)
void attn_kernel(const unsigned short* __restrict__ Qbf, const unsigned short* __restrict__ Kbf,
                 const unsigned short* __restrict__ VTbf,
                 const float* __restrict__ x_lig, const float* __restrict__ x_pocket,
                 const float* __restrict__ tabG,
                 unsigned* __restrict__ partOb, float4* __restrict__ partZC) {
  __shared__ float4 xch[CHUNK];            // 8 KB
  __shared__ float tab[NHEAD][NTAB];       // 16 KB

  int tid = threadIdx.x;
  int h = tid >> 6;
  int lane = tid & 63;
  int lo = lane & 31, hi = lane >> 5;
  int qt = blockIdx.x & 31;
  int split = blockIdx.x >> 5;
  int q0 = qt * 32;
  int j0g = split * CHUNK;

  for (int i = tid; i < CHUNK; i += 256) {
    float x = x_pocket[(j0g + i) * 3 + 0];
    float y = x_pocket[(j0g + i) * 3 + 1];
    float z = x_pocket[(j0g + i) * 3 + 2];
    float4 v; v.x = x; v.y = y; v.z = z; v.w = 0.f;
    xch[i] = v;
  }
  for (int i = tid; i < NHEAD * NTAB; i += 256) ((float*)tab)[i] = tabG[i];
  __syncthreads();

  int q = q0 + lo;
  float xl0 = x_lig[q * 3 + 0];
  float xl1 = x_lig[q * 3 + 1];
  float xl2 = x_lig[q * 3 + 2];

  short8 qfr[4];
#pragma unroll
  for (int kk = 0; kk < 4; ++kk)
    qfr[kk] = load_bf8(Qbf + t8(q, h * HDIM + kk * 16 + hi * 8, 32));

  // K tile-8 base: row j0g+lo (tile row j0g>>5), head cols h*64.. (+hi*8)
  const unsigned short* kbp = Kbf + t8(j0g + lo, h * HDIM + hi * 8, 32);
  // V^T tile-8 [256][8192]: rows h*64+lo / +32, cols j0g.. (+hi*8)
  const unsigned short* vbp = VTbf + t8(h * HDIM + lo, j0g + hi * 8, 1024);

  f32x16 O0, O1;
#pragma unroll
  for (int i = 0; i < 16; ++i) { O0[i] = 0.f; O1[i] = 0.f; }
  float Z = 0.f, c0 = 0.f, c1 = 0.f, c2 = 0.f;

  short8 kcur[4];
#pragma unroll
  for (int kk = 0; kk < 4; ++kk) kcur[kk] = load_bf8(kbp + kk * 512);

#pragma unroll 1
  for (int t = 0; t < NT; ++t) {
    int jb = t * 32;
    int tn = (t + 1 < NT) ? (t + 1) : t;
    // prefetch next K tile (tile-row stride = 32*256 = 8192 elems)
    short8 knx0 = load_bf8(kbp + (size_t)tn * 8192 + 0 * 512);
    short8 knx1 = load_bf8(kbp + (size_t)tn * 8192 + 1 * 512);
    short8 knx2 = load_bf8(kbp + (size_t)tn * 8192 + 2 * 512);
    short8 knx3 = load_bf8(kbp + (size_t)tn * 8192 + 3 * 512);
    // hoisted V loads: j advances 32 per t -> +4 tiles = +1024 elems;
    // sub advances 16 -> +512; O1 row-block +1 -> +1024*256 elems.
    short8 v00 = load_bf8(vbp + (size_t)t * 1024);
    short8 v01 = load_bf8(vbp + (size_t)t * 1024 + 262144);
    short8 v10 = load_bf8(vbp + (size_t)t * 1024 + 512);
    short8 v11 = load_bf8(vbp + (size_t)t * 1024 + 512 + 262144);

    f32x16 s;
#pragma unroll
    for (int i = 0; i < 16; ++i) s[i] = 0.f;
    s = mfma32(kcur[0], qfr[0], s);
    s = mfma32(kcur[1], qfr[1], s);
    s = mfma32(kcur[2], qfr[2], s);
    s = mfma32(kcur[3], qfr[3], s);

    unsigned wp[8];
    float pprev = 0.f;
#pragma unroll
    for (int r = 0; r < 16; ++r) {
      int jl = (r & 3) + 8 * (r >> 2) + 4 * hi;
      float4 xp = xch[jb + jl];
      float dx = xp.x - xl0, dy = xp.y - xl1, dz = xp.z - xl2;
      float r2 = fmaf(dx, dx, fmaf(dy, dy, dz * dz));
      float r2c = fmaxf(r2, 1e-24f);
      float rinv = rsqh(r2c);
      float d = r2c * rinv;
      int idx = (int)(d * (NTAB / 10.0f));
      idx = idx > (NTAB - 1) ? (NTAB - 1) : idx;
      float b = tab[h][idx];
      float s2 = fmaf(s[r], QK_SCALE, b);
      float pe = (r2 < 100.0f) ? exp2h(s2) : 0.0f;
      Z += pe;
      float pr = pe * rinv;
      c0 = fmaf(pr, dx, c0);
      c1 = fmaf(pr, dy, c1);
      c2 = fmaf(pr, dz, c2);
      if (r & 1) wp[r >> 1] = cvtpk(pprev, pe); else pprev = pe;
    }
    {
      unsigned W0 = wp[0], W1 = wp[1], W2 = wp[2], W3 = wp[3];
      unsigned e01 = (unsigned)__shfl_xor((int)(hi ? W0 : W2), 32);
      unsigned e23 = (unsigned)__shfl_xor((int)(hi ? W1 : W3), 32);
      U4S8 pb;
      pb.u.x = hi ? e01 : W0;
      pb.u.y = hi ? e23 : W1;
      pb.u.z = hi ? W2 : e01;
      pb.u.w = hi ? W3 : e23;
      O0 = mfma32(v00, pb.s, O0);
      O1 = mfma32(v01, pb.s, O1);
    }
    {
      unsigned W0 = wp[4], W1 = wp[5], W2 = wp[6], W3 = wp[7];
      unsigned e01 = (unsigned)__shfl_xor((int)(hi ? W0 : W2), 32);
      unsigned e23 = (unsigned)__shfl_xor((int)(hi ? W1 : W3), 32);
      U4S8 pb;
      pb.u.x = hi ? e01 : W0;
      pb.u.y = hi ? e23 : W1;
      pb.u.z = hi ? W2 : e01;
      pb.u.w = hi ? W3 : e23;
      O0 = mfma32(v10, pb.s, O0);
      O1 = mfma32(v11, pb.s, O1);
    }
    kcur[0] = knx0; kcur[1] = knx1; kcur[2] = knx2; kcur[3] = knx3;
  }

  // partO layout [split][q][c=256] (bf16), so combine reads coalesced.
  unsigned* po = partOb + ((size_t)(split * NLIG + q) * (HIDDEN / 2)) + h * (HDIM / 2);
#pragma unroll
  for (int g = 0; g < 4; ++g) {
    uint2 u0;
    u0.x = cvtpk(O0[g * 4 + 0], O0[g * 4 + 1]);
    u0.y = cvtpk(O0[g * 4 + 2], O0[g * 4 + 3]);
    *(uint2*)(po + g * 4 + hi * 2) = u0;
    uint2 u1;
    u1.x = cvtpk(O1[g * 4 + 0], O1[g * 4 + 1]);
    u1.y = cvtpk(O1[g * 4 + 2], O1[g * 4 + 3]);
    *(uint2*)(po + 16 + g * 4 + hi * 2) = u1;
  }
  float Zt = Z + __shfl_xor(Z, 32);
  float c0t = c0 + __shfl_xor(c0, 32);
  float c1t = c1 + __shfl_xor(c1, 32);
  float c2t = c2 + __shfl_xor(c2, 32);
  if (hi == 0) {
    float4 zc; zc.x = Zt; zc.y = c0t; zc.z = c1t; zc.w = c2t;
    partZC[(size_t)(split * NLIG + q) * NHEAD + h] = zc;
  }
}

// ------------- combine splits -> h_attended (tile-8 bf16) + coord msgs ------
__global__ __launch_bounds__(256)
void combine_kernel(const unsigned short* __restrict__ partOb, const float4* __restrict__ partZC,
                    unsigned short* __restrict__ hattb, float* __restrict__ cmsg) {
  int q = blockIdx.x;
  int t = threadIdx.x;
  int h = t >> 6;
  float Zh = 0.f;
#pragma unroll
  for (int s = 0; s < NSPLIT; ++s) Zh += partZC[(size_t)(s * NLIG + q) * NHEAD + h].x;
  float o = 0.f;
#pragma unroll
  for (int s = 0; s < NSPLIT; ++s)
    o += bf2f(partOb[(size_t)(s * NLIG + q) * HIDDEN + t]);   // coalesced
  float inv = (Zh > 0.f) ? 1.0f / Zh : 0.f;
  hattb[t8(q, t, 32)] = f2bf(o * inv);

  __shared__ float sm[NHEAD][3];
  if (t < NHEAD) {
    float zz = 0.f, a0 = 0.f, a1 = 0.f, a2 = 0.f;
    for (int s = 0; s < NSPLIT; ++s) {
      float4 v = partZC[(size_t)(s * NLIG + q) * NHEAD + t];
      zz += v.x; a0 += v.y; a1 += v.z; a2 += v.w;
    }
    float iv = (zz > 0.f) ? 0.25f / zz : 0.f;
    sm[t][0] = a0 * iv; sm[t][1] = a1 * iv; sm[t][2] = a2 * iv;
  }
  __syncthreads();
  if (t < 3) cmsg[q * 3 + t] = sm[0][t] + sm[1][t] + sm[2][t] + sm[3][t];
}

// ------------- fused epilogue: hout = hatt@ow + ob + resid ;  cscale --------
__global__ __launch_bounds__(256)
void epi_kernel(const unsigned short* __restrict__ hatt,
                const unsigned short* __restrict__ owT, const unsigned short* __restrict__ c1wT,
                const float* __restrict__ ob, const float* __restrict__ c1b,
                const float* __restrict__ c2w, const float* __restrict__ h_lig,
                float* __restrict__ hout, float* __restrict__ cscale) {
  int tid = threadIdx.x;
  int w = tid >> 6, lane = tid & 63;
  int lo = lane & 31, hi = lane >> 5;
  int m0 = blockIdx.x * 128 + w * 32;
  int n0 = blockIdx.y * 32;
  int n = n0 + lo;
  const unsigned short* ap = hatt + t8(m0 + lo, hi * 8, 32);
  const unsigned short* bo = owT + t8(n, hi * 8, 32);
  const unsigned short* bc = c1wT + t8(n, hi * 8, 32);
  f32x16 aO, aC;
#pragma unroll
  for (int i = 0; i < 16; ++i) { aO[i] = 0.f; aC[i] = 0.f; }
#pragma unroll 8
  for (int kk = 0; kk < HIDDEN / 16; ++kk) {
    short8 a  = load_bf8(ap + kk * 512);
    short8 b1 = load_bf8(bo + kk * 512);
    short8 b2 = load_bf8(bc + kk * 512);
    aO = mfma32(a, b1, aO);
    aC = mfma32(a, b2, aC);
  }
  float obn = ob[n], c1bn = c1b[n], c2wn = c2w[n];
#pragma unroll
  for (int g = 0; g < 4; ++g) {
#pragma unroll
    for (int rr = 0; rr < 4; ++rr) {
      int r = g * 4 + rr;
      int m = m0 + g * 8 + hi * 4 + rr;
      hout[(size_t)m * HIDDEN + n] = aO[r] + obn + h_lig[(size_t)m * HIDDEN + n];
      float v = aC[r] + c1bn;
      float sg = v / (1.0f + exp2h(-LOG2E * v));
      float part = sg * c2wn;
#pragma unroll
      for (int msk = 16; msk >= 1; msk >>= 1) part += __shfl_xor(part, msk);
      if (lo == 0) atomicAdd(&cscale[m], part);
    }
  }
}

// ------------- coord finish: x_out = x_lig + (cscale+c2b)*cmsg --------------
__global__ __launch_bounds__(256)
void coordfin_kernel(const float* __restrict__ cscale, const float* __restrict__ c2b,
                     const float* __restrict__ cmsg, const float* __restrict__ x_lig,
                     float* __restrict__ x_out) {
  int id = blockIdx.x * 256 + threadIdx.x;
  if (id < NLIG * 3) {
    int q = id / 3;
    x_out[id] = x_lig[id] + (cscale[q] + c2b[0]) * cmsg[id];
  }
}

extern "C" void kernel_launch(void* const* d_in, const int* in_sizes, int n_in,
                              void* d_out, int out_size, void* d_ws, size_t ws_size,
                              hipStream_t stream) {
  const float* h_lig  = (const float*)d_in[0];
  const float* x_lig  = (const float*)d_in[1];
  const float* h_atom = (const float*)d_in[2];
  const float* x_pock = (const float*)d_in[3];
  const float* qw  = (const float*)d_in[4];
  const float* qb  = (const float*)d_in[5];
  const float* kw  = (const float*)d_in[6];
  const float* kb  = (const float*)d_in[7];
  const float* vw  = (const float*)d_in[8];
  const float* vb  = (const float*)d_in[9];
  const float* ow  = (const float*)d_in[10];
  const float* ob  = (const float*)d_in[11];
  const float* e1w = (const float*)d_in[12];
  const float* e1b = (const float*)d_in[13];
  const float* e2w = (const float*)d_in[14];
  const float* e2b = (const float*)d_in[15];
  const float* c1w = (const float*)d_in[16];
  const float* c1b = (const float*)d_in[17];
  const float* c2w = (const float*)d_in[18];
  const float* c2b = (const float*)d_in[19];

  char* w = (char*)d_ws;
  unsigned short* hAb  = (unsigned short*)w; w += (size_t)NPOCK * ADIM * 2;
  unsigned short* hlb  = (unsigned short*)w; w += (size_t)NLIG * HIDDEN * 2;
  unsigned short* qwT  = (unsigned short*)w; w += 256 * 256 * 2;
  unsigned short* kwT  = (unsigned short*)w; w += 256 * 512 * 2;
  unsigned short* vwT  = (unsigned short*)w; w += 256 * 512 * 2;
  unsigned short* owT  = (unsigned short*)w; w += 256 * 256 * 2;
  unsigned short* c1wT = (unsigned short*)w; w += 256 * 256 * 2;
  unsigned short* Qb   = (unsigned short*)w; w += (size_t)NLIG * HIDDEN * 2;
  unsigned short* Kb   = (unsigned short*)w; w += (size_t)NPOCK * HIDDEN * 2;
  unsigned short* VTb  = (unsigned short*)w; w += (size_t)HIDDEN * NPOCK * 2;
  float* tabG          = (float*)w;          w += NHEAD * NTAB * 4;
  unsigned* partOb     = (unsigned*)w;       w += (size_t)NSPLIT * NLIG * HIDDEN * 2;
  float* partZC        = (float*)w;          w += (size_t)NSPLIT * NLIG * NHEAD * 4 * 4;
  unsigned short* hatt = (unsigned short*)w; w += (size_t)NLIG * HIDDEN * 2;
  float* cmsg          = (float*)w;          w += (size_t)NLIG * 3 * 4;
  float* cscale        = (float*)w;          w += (size_t)NLIG * 4;

  float* hout = (float*)d_out;
  float* xout = ((float*)d_out) + (size_t)NLIG * HIDDEN;

  prep_kernel<<<NCAST + NTRANS + NTAB / 4, 256, 0, stream>>>(
      h_atom, h_lig, qw, kw, vw, ow, c1w, e1w, e1b, e2w, e2b,
      hAb, hlb, qwT, kwT, vwT, owT, c1wT, tabG);
  proj_kernel<<<dim3(72, 8), 256, 0, stream>>>(
      hAb, hlb, kwT, vwT, qwT, kb, vb, qb, Kb, VTb, Qb);
  attn_kernel<<<32 * NSPLIT, 256, 0, stream>>>(Qb, Kb, VTb, x_lig, x_pock, tabG,
                                               partOb, (float4*)partZC);
  combine_kernel<<<NLIG, 256, 0, stream>>>((const unsigned short*)partOb,
                                           (const float4*)partZC, hatt, cmsg);
  hipMemsetAsync(cscale, 0, NLIG * sizeof(float), stream);
  epi_kernel<<<dim3(8, 8), 256, 0, stream>>>(hatt, owT, c1wT, ob, c1b, c2w, h_lig,
                                             hout, cscale);
  coordfin_kernel<<<(NLIG * 3 + 255) / 256, 256, 0, stream>>>(cscale, c2b, cmsg,
                                                              x_lig, xout);
}